// Round 6
// baseline (264.097 us; speedup 1.0000x reference)
//
#include <hip/hip_runtime.h>
#include <hip/hip_bf16.h>

typedef __attribute__((ext_vector_type(8))) short short8;
typedef __attribute__((ext_vector_type(4))) float f32x4;

#define MFMA16(a,b,c) __builtin_amdgcn_mfma_f32_16x16x32_bf16((a),(b),(c),0,0,0)

static __device__ __forceinline__ unsigned short f2b(float f){
  __hip_bfloat16 h = __float2bfloat16(f);
  return __builtin_bit_cast(unsigned short, h);
}
static __device__ __forceinline__ float b2f(unsigned short u){
  unsigned int v = ((unsigned int)u)<<16;
  return __builtin_bit_cast(float, v);
}

static __device__ __forceinline__ void gld_lds16(const void* g, void* l){
  __builtin_amdgcn_global_load_lds((const __attribute__((address_space(1))) unsigned int*)g,
                                   (__attribute__((address_space(3))) unsigned int*)l, 16, 0, 0);
}

// ---------------- elementwise f32 -> bf16 ----------------
__global__ __launch_bounds__(256) void k_convert_x(const float* __restrict__ x,
                                                   unsigned short* __restrict__ xb, int n){
  int i = (blockIdx.x*256 + threadIdx.x)*8;
  if (i >= n) return;
  float4 a = *(const float4*)(x+i);
  float4 b = *(const float4*)(x+i+4);
  short8 v;
  v[0]=f2b(a.x); v[1]=f2b(a.y); v[2]=f2b(a.z); v[3]=f2b(a.w);
  v[4]=f2b(b.x); v[5]=f2b(b.y); v[6]=f2b(b.z); v[7]=f2b(b.w);
  *(short8*)(xb+i) = v;
}

// ---------------- transpose + convert: in f32 [R][C] -> out bf16 [C][R] ----------------
__global__ void k_transpose_convert(const float* __restrict__ in,
                                    unsigned short* __restrict__ out, int R, int C){
  __shared__ float tile[32][33];
  int c0 = blockIdx.x*32, r0 = blockIdx.y*32;
  int tx = threadIdx.x, ty = threadIdx.y;
  #pragma unroll
  for (int i=0;i<4;i++) tile[ty*4+i][tx] = in[(size_t)(r0+ty*4+i)*C + c0+tx];
  __syncthreads();
  #pragma unroll
  for (int i=0;i<4;i++) out[(size_t)(c0+ty*4+i)*R + r0+tx] = f2b(tile[tx][ty*4+i]);
}

// ---------------- 256xBN pipelined-phase bf16 GEMM: C = A[M][K] * BT[N][K]^T ----------------
// Key mechanism: each phase issues the NEXT phase's frag ds_reads, then waits a
// COUNTED lgkmcnt so current frags are ready while next-phase reads overlap the
// MFMA cluster. 1 barrier/phase (4/K-tile). Stages: B regions (t+2) in window 2,
// A in window 3 (WAR-safe by lgkm evidence + barrier). Counted vmcnt per tile.
// XOR-8 chunk swizzle both-sides (round-4 proven, 0 conflicts). XCD swizzle.
template<int OB, int BN>   // OB=1: bf16 C out; BN in {256,128}
__global__ __launch_bounds__(512,2) void k_gemm8(const unsigned short* __restrict__ A,
    const unsigned short* __restrict__ BT, void* __restrict__ Cv,
    int M, int N, int K, int nbx){
  constexpr int BCH = (BN==256) ? 1024 : 512;   // 16B chunks per B region
  constexpr int NACC = (BN==256) ? 4 : 2;
  __shared__ __align__(16) unsigned short lds[(4096 + 4*BCH)*8];
  const int NT = K >> 6;                         // K-tiles (even: K=2048 -> 32)
  int cpx = gridDim.x >> 3;
  int bid = blockIdx.x;
  int swz = (bid & 7)*cpx + (bid >> 3);
  int bm = (swz / nbx)*256, bn = (swz % nbx)*BN;
  int tid = threadIdx.x;
  int wave = tid >> 6, lane = tid & 63;
  int r = lane & 15, g = lane >> 4;
  int wr  = wave >> 2;                  // A half (M)
  int wcq = wave & 3;
  int wcH = wcq >> 1;                   // B half
  int brow = (BN==256) ? (wcq & 1)*64 : (wcq & 1)*32;

  f32x4 acc[8][NACC];
  #pragma unroll
  for (int i=0;i<8;i++)
    #pragma unroll
    for (int j=0;j<NACC;j++){ acc[i][j][0]=0.f; acc[i][j][1]=0.f; acc[i][j][2]=0.f; acc[i][j][3]=0.f; }

  // region chunk bases: A: (p*2+H)*1024 ; B: 4096 + (p*2+H)*BCH
  #define LDSC(ch) (*(const short8*)((const char*)lds + ((size_t)(ch)<<4)))
  #define STG_A(p,H,t) do{ int ts_ = ((t) < NT) ? (t) : (NT-1);                         \
    _Pragma("unroll") for (int i_=0;i_<2;++i_){ int c_ = tid + i_*512;                  \
      int row_ = c_>>3, kc_ = c_&7;                                                     \
      gld_lds16(&A[(size_t)(bm + (H)*128 + row_)*K + (size_t)ts_*64 + ((kc_^(row_&7))*8)], \
                (char*)lds + ((size_t)(((p)*2+(H))*1024 + c_)<<4)); } }while(0)
  #define STG_B(p,H,t) do{ int ts_ = ((t) < NT) ? (t) : (NT-1);                         \
    _Pragma("unroll") for (int i_=0;i_<(BCH/512);++i_){ int c_ = tid + i_*512;          \
      int row_ = c_>>3, kc_ = c_&7;                                                     \
      gld_lds16(&BT[(size_t)(bn + (H)*(BCH/8) + row_)*K + (size_t)ts_*64 + ((kc_^(row_&7))*8)], \
                (char*)lds + ((size_t)(4096 + ((p)*2+(H))*BCH + c_)<<4)); } }while(0)

  #define LDA8(dst,p,frb) _Pragma("unroll") for (int fr_=0;fr_<4;++fr_)                 \
      _Pragma("unroll") for (int kk_=0;kk_<2;++kk_){ int row_ = ((frb)+fr_)*16 + r;     \
        dst[fr_][kk_] = LDSC(((p)*2+wr)*1024 + row_*8 + ((kk_*4+g)^(row_&7))); }
  #define LDB4(dst,p,fcb) _Pragma("unroll") for (int fc_=0;fc_<2;++fc_)                 \
      _Pragma("unroll") for (int kk_=0;kk_<2;++kk_){ int row_ = brow + ((fcb)+fc_)*16 + r; \
        dst[fc_][kk_] = LDSC(4096 + ((p)*2+wcH)*BCH + row_*8 + ((kk_*4+g)^(row_&7))); }
  #define LDBK(dst,p,kk) _Pragma("unroll") for (int fc_=0;fc_<2;++fc_){                 \
        int row_ = brow + fc_*16 + r;                                                   \
        dst[fc_][kk] = LDSC(4096 + ((p)*2+wcH)*BCH + row_*8 + (((kk)*4+g)^(row_&7))); }

  #define MMA8(ar,ac,afv,bfv) _Pragma("unroll") for (int kk_=0;kk_<2;++kk_)             \
      _Pragma("unroll") for (int fr_=0;fr_<4;++fr_)                                     \
      _Pragma("unroll") for (int fc_=0;fc_<2;++fc_)                                     \
        acc[(ar)+fr_][(ac)+fc_] = MFMA16(afv[fr_][kk_], bfv[fc_][kk_], acc[(ar)+fr_][(ac)+fc_]);
  #define MMAK(ar,afv,kk) _Pragma("unroll") for (int fr_=0;fr_<4;++fr_)                 \
      _Pragma("unroll") for (int fc_=0;fc_<2;++fc_)                                     \
        acc[(ar)+fr_][fc_] = MFMA16(afv[fr_][kk], bfx[fc_][kk], acc[(ar)+fr_][fc_]);

  #define BAR() asm volatile("s_barrier" ::: "memory")
  #define LGKM(n) do{ asm volatile("s_waitcnt lgkmcnt(" #n ")" ::: "memory");           \
                      __builtin_amdgcn_sched_barrier(0); }while(0)
  #define VM(n) asm volatile("s_waitcnt vmcnt(" #n ")" ::: "memory")
  #define PRIO1 __builtin_amdgcn_s_setprio(1)
  #define PRIO0 __builtin_amdgcn_s_setprio(0)

  if constexpr (BN==256){
    short8 af_lo[4][2], af_hi[4][2], bf0[2][2], bf1[2][2];
    // prologue: stage t0 (A,B), then B(t1), A(t1); drain t0, prefetch t0 frags
    STG_A(0,0,0); STG_A(0,1,0); STG_B(0,0,0); STG_B(0,1,0);
    STG_B(1,0,1); STG_B(1,1,1); STG_A(1,0,1); STG_A(1,1,1);
    VM(8); BAR();
    LDA8(af_lo,0,0); LDB4(bf0,0,0);

    #define KT256(p,t) do{                                                              \
      /*P0*/ LDB4(bf1,p,2);                                                             \
      BAR(); LGKM(4);                                                                   \
      PRIO1; MMA8(0,0,af_lo,bf0); PRIO0;                                                \
      /*P1*/ LDA8(af_hi,p,4);                                                           \
      BAR(); LGKM(8);                                                                   \
      PRIO1; MMA8(0,2,af_lo,bf1); PRIO0;                                                \
      /*P2*/ BAR(); LGKM(0);                                                            \
      STG_B(p,0,(t)+2); STG_B(p,1,(t)+2);                                               \
      PRIO1; MMA8(4,0,af_hi,bf0); PRIO0;                                                \
      /*P3*/ VM(4);                                                                     \
      BAR(); __builtin_amdgcn_sched_barrier(0);                                         \
      STG_A(p,0,(t)+2); STG_A(p,1,(t)+2);                                               \
      LDA8(af_lo,(p)^1,0); LDB4(bf0,(p)^1,0);                                           \
      PRIO1; MMA8(4,2,af_hi,bf1); PRIO0;                                                \
    }while(0)

    for (int tt=0; tt<NT; tt+=2){ KT256(0,tt); KT256(1,tt+1); }
    #undef KT256
  } else {
    short8 af_lo[4][2], af_hi[4][2], bfx[2][2];
    STG_A(0,0,0); STG_A(0,1,0); STG_B(0,0,0); STG_B(0,1,0);
    STG_B(1,0,1); STG_B(1,1,1); STG_A(1,0,1); STG_A(1,1,1);
    VM(6); BAR();
    LDA8(af_lo,0,0); LDBK(bfx,0,0);

    #define KT128(p,t) do{                                                              \
      /*P0*/ LDBK(bfx,p,1);                                                             \
      BAR(); LGKM(2);                                                                   \
      PRIO1; MMAK(0,af_lo,0); PRIO0;                                                    \
      /*P1*/ LDA8(af_hi,p,4);                                                           \
      BAR(); LGKM(8);                                                                   \
      PRIO1; MMAK(0,af_lo,1); PRIO0;                                                    \
      /*P2*/ BAR(); LGKM(0);                                                            \
      STG_B(p,0,(t)+2); STG_B(p,1,(t)+2);                                               \
      PRIO1; MMAK(4,af_hi,0); PRIO0;                                                    \
      /*P3*/ VM(2);                                                                     \
      BAR(); __builtin_amdgcn_sched_barrier(0);                                         \
      STG_A(p,0,(t)+2); STG_A(p,1,(t)+2);                                               \
      LDA8(af_lo,(p)^1,0); LDBK(bfx,(p)^1,0);                                           \
      PRIO1; MMAK(4,af_hi,1); PRIO0;                                                    \
    }while(0)

    for (int tt=0; tt<NT; tt+=2){ KT128(0,tt); KT128(1,tt+1); }
    #undef KT128
  }

  int bcol0 = (BN==256) ? (wcH*128 + brow) : (wcH*64 + brow);
  #pragma unroll
  for (int i=0;i<8;i++)
    #pragma unroll
    for (int j=0;j<NACC;j++)
      #pragma unroll
      for (int rr=0;rr<4;rr++){
        size_t idx = (size_t)(bm + wr*128 + i*16 + 4*g + rr)*N + bn + bcol0 + j*16 + r;
        if (OB) ((unsigned short*)Cv)[idx] = f2b(acc[i][j][rr]);
        else    ((float*)Cv)[idx] = acc[i][j][rr];
      }

  #undef LDSC
  #undef STG_A
  #undef STG_B
  #undef LDA8
  #undef LDB4
  #undef LDBK
  #undef MMA8
  #undef MMAK
  #undef BAR
  #undef LGKM
  #undef VM
  #undef PRIO1
  #undef PRIO0
}

// ---------------- RoPE + head split (bf16 qkv in); Q scaled by log2(e)/sqrt(128) ----------------
__global__ __launch_bounds__(256) void k_rope_split(const unsigned short* __restrict__ qkv,
    const float* __restrict__ fc, unsigned short* __restrict__ qb,
    unsigned short* __restrict__ kb, unsigned short* __restrict__ vb){
  int row = blockIdx.x;              // b*2048 + t
  int t = row & 2047, b = row >> 11;
  int tid = threadIdx.x;
  const unsigned short* qr = qkv + (size_t)row*3072;
  const float QS = 0.12751743f;      // log2(e)/sqrt(128)
  #pragma unroll
  for (int ii=0; ii<4; ii++){        // 1024 q pairs
    int p = tid + 256*ii;
    int h = p>>6, f = p&63;
    unsigned int pr = *(const unsigned int*)&qr[h*128 + 2*f];
    float x0 = b2f((unsigned short)(pr & 0xffff)), x1 = b2f((unsigned short)(pr >> 16));
    float2 cssn = *(const float2*)&fc[t*128 + 2*f];
    float o0 = (x0*cssn.x - x1*cssn.y)*QS, o1 = (x0*cssn.y + x1*cssn.x)*QS;
    size_t o = ((size_t)(b*16 + h)*2048 + t)*128 + 2*f;
    qb[o] = f2b(o0); qb[o+1] = f2b(o1);
  }
  {                                   // 256 k pairs
    int p = tid; int kh = p>>6, f = p&63;
    unsigned int pr = *(const unsigned int*)&qr[2048 + kh*128 + 2*f];
    float x0 = b2f((unsigned short)(pr & 0xffff)), x1 = b2f((unsigned short)(pr >> 16));
    float2 cssn = *(const float2*)&fc[t*128 + 2*f];
    float o0 = x0*cssn.x - x1*cssn.y, o1 = x0*cssn.y + x1*cssn.x;
    size_t o = ((size_t)(b*4 + kh)*2048 + t)*128 + 2*f;
    kb[o] = f2b(o0); kb[o+1] = f2b(o1);
  }
  #pragma unroll
  for (int ii=0; ii<2; ii++){         // 512 v elems
    int e = tid + 256*ii;
    int kh = e>>7, d = e&127;
    size_t o = ((size_t)(b*4 + kh)*2048 + t)*128 + d;
    vb[o] = qr[2560 + e];
  }
}

// ---------------- V transpose: [bk][2048][128] -> [bk][128][2048] ----------------
__global__ void k_transpose_v(const unsigned short* __restrict__ v,
                              unsigned short* __restrict__ vt){
  __shared__ unsigned short tile[32][33];
  int bk = blockIdx.z;
  int d0 = blockIdx.x*32, t0 = blockIdx.y*32;
  int tx = threadIdx.x, ty = threadIdx.y;
  const unsigned short* vp = v + (size_t)bk*2048*128;
  unsigned short* vtp = vt + (size_t)bk*128*2048;
  #pragma unroll
  for (int i=0;i<4;i++) tile[ty*4+i][tx] = vp[(t0+ty*4+i)*128 + d0+tx];
  __syncthreads();
  #pragma unroll
  for (int i=0;i<4;i++) vtp[(d0+ty*4+i)*2048 + t0+tx] = tile[tx][ty*4+i];
}

// ---------------- sliding-window flash attention, LDS-staged K/V ----------------
__global__ __launch_bounds__(256,2) void k_attn(const unsigned short* __restrict__ q,
    const unsigned short* __restrict__ k, const unsigned short* __restrict__ vt,
    unsigned short* __restrict__ y){
  int qb0 = blockIdx.x*64;
  int h = blockIdx.y, b = blockIdx.z;
  int kvh = h>>2;
  int tid = threadIdx.x, wave = tid>>6, lane = tid&63;
  int w0 = qb0 + wave*16;
  int r = lane&15, g = lane>>4;
  const unsigned short* qh = q + ((size_t)(b*16+h)*2048)*128;
  const unsigned short* kh = k + ((size_t)(b*4+kvh)*2048)*128;
  const unsigned short* vh = vt + ((size_t)(b*4+kvh)*128)*2048;

  __shared__ unsigned short Ks[2][64*128];   // [key][d], swizzled
  __shared__ unsigned short Vs[2][128*64];   // [d][key], swizzled
  __shared__ unsigned short plds[4][16][72];

  short8 qf[4];
  #pragma unroll
  for (int c=0;c<4;c++) qf[c] = *(const short8*)&qh[(w0+r)*128 + c*32 + g*8];

  f32x4 acc[8];
  #pragma unroll
  for (int d=0; d<8; d++){ acc[d][0]=0.f; acc[d][1]=0.f; acc[d][2]=0.f; acc[d][3]=0.f; }
  float m[4]  = {-1e30f,-1e30f,-1e30f,-1e30f};
  float ls[4] = {0.f,0.f,0.f,0.f};

  int lo = qb0 - 511; if (lo < 0) lo = 0;
  int t0 = lo & ~63;
  int nt = ((qb0 + 63) - t0)/64 + 1;
  int sw = (r&7)<<4;                 // per-lane read swizzle (row&7 == r&7)

  #define STAGE(bb, kt)                                                          \
    { _Pragma("unroll")                                                          \
      for (int p=0;p<4;p++){                                                     \
        int c = p*256 + tid;                                                     \
        int row = c>>4, col = (c&15)*16;                                         \
        gld_lds16((const char*)kh + (size_t)((kt)+row)*256 + (col ^ ((row&7)<<4)),\
                  (char*)&Ks[bb][0] + c*16);                                     \
      }                                                                          \
      _Pragma("unroll")                                                          \
      for (int p=0;p<4;p++){                                                     \
        int c = p*256 + tid;                                                     \
        int row = c>>3, col = (c&7)*16;                                          \
        gld_lds16((const char*)vh + (size_t)row*4096 + (size_t)(kt)*2 + (col ^ ((row&7)<<4)),\
                  (char*)&Vs[bb][0] + c*16);                                     \
      }                                                                          \
    }

  STAGE(0, t0);
  __syncthreads();
  int cur = 0;

  for (int it=0; it<nt; it++){
    int kt = t0 + it*64;
    if (it+1 < nt) STAGE(cur^1, t0 + (it+1)*64);

    bool use = (kt <= w0+15) && (kt+63 >= w0-511);
    if (use){
      f32x4 S[4];
      #pragma unroll
      for (int s=0;s<4;s++){
        f32x4 a; a[0]=0.f; a[1]=0.f; a[2]=0.f; a[3]=0.f;
        const char* kr = (const char*)&Ks[cur][0] + (s*16+r)*256;
        #pragma unroll
        for (int c=0;c<4;c++){
          short8 kf = *(const short8*)(kr + ((c*64 + g*16) ^ sw));
          a = MFMA16(qf[c], kf, a);
        }
        S[s] = a;
      }
      #pragma unroll
      for (int rr=0;rr<4;rr++){
        int i = w0 + 4*g + rr;
        float mx = -3e38f;
        #pragma unroll
        for (int s=0;s<4;s++){
          int j = kt + s*16 + r;
          bool valid = (j <= i) && (i - j < 512);
          float sv = valid ? S[s][rr] : -3e38f;
          S[s][rr] = sv;
          mx = fmaxf(mx, sv);
        }
        mx = fmaxf(mx, __shfl_xor(mx, 1));
        mx = fmaxf(mx, __shfl_xor(mx, 2));
        mx = fmaxf(mx, __shfl_xor(mx, 4));
        mx = fmaxf(mx, __shfl_xor(mx, 8));
        float mn = fmaxf(m[rr], mx);
        float al = exp2f(m[rr] - mn);
        m[rr] = mn;
        float ps = 0.f;
        #pragma unroll
        for (int s=0;s<4;s++){
          float p = exp2f(S[s][rr] - mn);
          S[s][rr] = p;
          ps += p;
        }
        ls[rr] = ls[rr]*al + ps;
        #pragma unroll
        for (int d=0;d<8;d++) acc[d][rr] *= al;
      }
      #pragma unroll
      for (int rr=0;rr<4;rr++)
        #pragma unroll
        for (int s=0;s<4;s++)
          plds[wave][4*g+rr][s*16+r] = f2b(S[s][rr]);
      short8 pf0 = *(const short8*)&plds[wave][r][g*8];
      short8 pf1 = *(const short8*)&plds[wave][r][32 + g*8];
      #pragma unroll
      for (int d=0;d<8;d++){
        const char* vr = (const char*)&Vs[cur][0] + (d*16+r)*128;
        short8 vf0 = *(const short8*)(vr + ((g*16) ^ sw));
        short8 vf1 = *(const short8*)(vr + ((64 + g*16) ^ sw));
        acc[d] = MFMA16(pf0, vf0, acc[d]);
        acc[d] = MFMA16(pf1, vf1, acc[d]);
      }
    }
    __syncthreads();
    cur ^= 1;
  }

  #pragma unroll
  for (int rr=0;rr<4;rr++){
    float s = ls[rr];
    s += __shfl_xor(s, 1);
    s += __shfl_xor(s, 2);
    s += __shfl_xor(s, 4);
    s += __shfl_xor(s, 8);
    float inv = 1.f/s;
    int i = w0 + 4*g + rr;
    #pragma unroll
    for (int d=0;d<8;d++)
      y[((size_t)(b*2048)+i)*2048 + h*128 + d*16 + r] = f2b(acc[d][rr]*inv);
  }
}

extern "C" void kernel_launch(void* const* d_in, const int* in_sizes, int n_in,
                              void* d_out, int out_size, void* d_ws, size_t ws_size,
                              hipStream_t stream) {
  const float* x      = (const float*)d_in[0];
  const float* w_attn = (const float*)d_in[1];
  const float* w_proj = (const float*)d_in[2];
  const float* fc     = (const float*)d_in[3];
  float* out = (float*)d_out;
  char* ws = (char*)d_ws;
  unsigned short* xb   = (unsigned short*)(ws);             // 16,777,216  x bf16
  unsigned short* wt   = (unsigned short*)(ws + 16777216);  // 12,582,912  w^T bf16 (reused)
  unsigned short* qkvb = (unsigned short*)(ws + 29360128);  // 25,165,824  qkv bf16
  unsigned short* yb   = (unsigned short*)(ws + 29360128);  // reuse after rope
  unsigned short* qb   = (unsigned short*)(ws + 54525952);  // 16,777,216
  unsigned short* kb   = (unsigned short*)(ws + 71303168);  //  4,194,304
  unsigned short* vb   = (unsigned short*)(ws + 75497472);  //  4,194,304
  unsigned short* vtb  = (unsigned short*)(ws + 79691776);  //  4,194,304

  k_convert_x<<<4096, 256, 0, stream>>>(x, xb, 8388608);
  k_transpose_convert<<<dim3(96,64), dim3(32,8), 0, stream>>>(w_attn, wt, 2048, 3072);
  k_gemm8<1,256><<<dim3(192), 512, 0, stream>>>(xb, wt, qkvb, 4096, 3072, 2048, 12);
  k_rope_split<<<4096, 256, 0, stream>>>(qkvb, fc, qb, kb, vb);
  k_transpose_v<<<dim3(4,64,8), dim3(32,8), 0, stream>>>(vb, vtb);
  k_transpose_convert<<<dim3(64,64), dim3(32,8), 0, stream>>>(w_proj, wt, 2048, 2048);
  k_attn<<<dim3(32,16,2), 256, 0, stream>>>(qb, kb, vtb, yb);
  k_gemm8<0,128><<<dim3(256), 512, 0, stream>>>(yb, wt, out, 4096, 2048, 2048, 16);
}

// Round 7
// 181.287 us; speedup vs baseline: 1.4568x; 1.4568x over previous
//
#include <hip/hip_runtime.h>
#include <hip/hip_bf16.h>

typedef __attribute__((ext_vector_type(8))) short short8;
typedef __attribute__((ext_vector_type(4))) float f32x4;

#define MFMA16(a,b,c) __builtin_amdgcn_mfma_f32_16x16x32_bf16((a),(b),(c),0,0,0)

static __device__ __forceinline__ unsigned short f2b(float f){
  __hip_bfloat16 h = __float2bfloat16(f);
  return __builtin_bit_cast(unsigned short, h);
}
static __device__ __forceinline__ float b2f(unsigned short u){
  unsigned int v = ((unsigned int)u)<<16;
  return __builtin_bit_cast(float, v);
}

static __device__ __forceinline__ void gld_lds16(const void* g, void* l){
  __builtin_amdgcn_global_load_lds((const __attribute__((address_space(1))) unsigned int*)g,
                                   (__attribute__((address_space(3))) unsigned int*)l, 16, 0, 0);
}

// ---------------- fused prep: convert x + transpose-convert both weights ----------------
// bid [0,4096): x f32->bf16 ; [4096,10240): w_attn^T ; [10240,14336): w_proj^T
__global__ __launch_bounds__(256) void k_prep(const float* __restrict__ x,
    const float* __restrict__ wA, const float* __restrict__ wP,
    unsigned short* __restrict__ xb, unsigned short* __restrict__ wtA,
    unsigned short* __restrict__ wtP){
  int bid = blockIdx.x, tid = threadIdx.x;
  if (bid < 4096){
    int i = (bid*256 + tid)*8;
    float4 a = *(const float4*)(x+i);
    float4 b = *(const float4*)(x+i+4);
    short8 v;
    v[0]=f2b(a.x); v[1]=f2b(a.y); v[2]=f2b(a.z); v[3]=f2b(a.w);
    v[4]=f2b(b.x); v[5]=f2b(b.y); v[6]=f2b(b.z); v[7]=f2b(b.w);
    *(short8*)(xb+i) = v;
    return;
  }
  __shared__ float tile[32][33];
  const float* in; unsigned short* out; int R, C, bx, by;
  if (bid < 10240){ int tt = bid-4096;  in=wA; out=wtA; R=2048; C=3072; bx=tt%96; by=tt/96; }
  else            { int tt = bid-10240; in=wP; out=wtP; R=2048; C=2048; bx=tt%64; by=tt/64; }
  int c0 = bx*32, r0 = by*32;
  int tx = tid&31, ty = tid>>5;
  #pragma unroll
  for (int i=0;i<4;i++) tile[ty*4+i][tx] = in[(size_t)(r0+ty*4+i)*C + c0+tx];
  __syncthreads();
  #pragma unroll
  for (int i=0;i<4;i++) out[(size_t)(c0+ty*4+i)*R + r0+tx] = f2b(tile[tx][ty*4+i]);
}

// ---------------- 128x128 m97-structure bf16 GEMM: C = A[M][K] * BT[N][K]^T ----------------
// Single-buffered 32KB LDS, BK=64, global_load_lds w16, 2 barriers/K-step,
// XOR-8 chunk swizzle both-sides (0 conflicts), XCD swizzle, >=2 blocks/CU.
template<int OB>   // OB=1: bf16 C out, OB=0: f32 C out
__global__ __launch_bounds__(256,2) void k_gemm97(const unsigned short* __restrict__ A,
    const unsigned short* __restrict__ BT, void* __restrict__ Cv,
    int M, int N, int K, int nbx){
  __shared__ __align__(16) unsigned short As[128*64];
  __shared__ __align__(16) unsigned short Bs[128*64];
  const int NT = K >> 6;
  int cpx = gridDim.x >> 3;
  int bid = blockIdx.x;
  int swz = (bid & 7)*cpx + (bid >> 3);
  int bm = (swz / nbx)*128, bn = (swz % nbx)*128;
  int tid = threadIdx.x;
  int wave = tid >> 6, lane = tid & 63;
  int r = lane & 15, g = lane >> 4;
  int wr = (wave >> 1)*64, wc = (wave & 1)*64;
  int sw = r & 7;

  f32x4 acc[4][4];
  #pragma unroll
  for (int i=0;i<4;i++)
    #pragma unroll
    for (int j=0;j<4;j++){ acc[i][j][0]=0.f; acc[i][j][1]=0.f; acc[i][j][2]=0.f; acc[i][j][3]=0.f; }

  for (int t=0; t<NT; ++t){
    // stage tile t (A 16KB + B 16KB), linear LDS dest + inverse-swizzled source
    #pragma unroll
    for (int i=0;i<4;i++){
      int c = i*256 + tid;
      int row = c>>3, kc = c&7;
      gld_lds16(&A[(size_t)(bm+row)*K + (size_t)t*64 + ((kc^(row&7))*8)], (char*)As + c*16);
    }
    #pragma unroll
    for (int i=0;i<4;i++){
      int c = i*256 + tid;
      int row = c>>3, kc = c&7;
      gld_lds16(&BT[(size_t)(bn+row)*K + (size_t)t*64 + ((kc^(row&7))*8)], (char*)Bs + c*16);
    }
    __syncthreads();
    short8 af[4][2], bf[4][2];
    #pragma unroll
    for (int i=0;i<4;i++)
      #pragma unroll
      for (int kk=0;kk<2;kk++){
        int row = wr + i*16 + r;
        af[i][kk] = *(const short8*)((const char*)As + ((size_t)(row*8 + ((kk*4+g)^sw))<<4));
      }
    #pragma unroll
    for (int j=0;j<4;j++)
      #pragma unroll
      for (int kk=0;kk<2;kk++){
        int row = wc + j*16 + r;
        bf[j][kk] = *(const short8*)((const char*)Bs + ((size_t)(row*8 + ((kk*4+g)^sw))<<4));
      }
    #pragma unroll
    for (int kk=0;kk<2;kk++)
      #pragma unroll
      for (int i=0;i<4;i++)
        #pragma unroll
        for (int j=0;j<4;j++)
          acc[i][j] = MFMA16(af[i][kk], bf[j][kk], acc[i][j]);
    __syncthreads();
  }

  #pragma unroll
  for (int i=0;i<4;i++)
    #pragma unroll
    for (int j=0;j<4;j++)
      #pragma unroll
      for (int rr=0;rr<4;rr++){
        size_t idx = (size_t)(bm + wr + i*16 + 4*g + rr)*N + bn + wc + j*16 + r;
        if (OB) ((unsigned short*)Cv)[idx] = f2b(acc[i][j][rr]);
        else    ((float*)Cv)[idx] = acc[i][j][rr];
      }
}

// ---------------- RoPE + head split (bf16 qkv in); Q scaled by log2(e)/sqrt(128) ----------------
__global__ __launch_bounds__(256) void k_rope_split(const unsigned short* __restrict__ qkv,
    const float* __restrict__ fc, unsigned short* __restrict__ qb,
    unsigned short* __restrict__ kb, unsigned short* __restrict__ vb){
  int row = blockIdx.x;              // b*2048 + t
  int t = row & 2047, b = row >> 11;
  int tid = threadIdx.x;
  const unsigned short* qr = qkv + (size_t)row*3072;
  const float QS = 0.12751743f;      // log2(e)/sqrt(128)
  #pragma unroll
  for (int ii=0; ii<4; ii++){        // 1024 q pairs
    int p = tid + 256*ii;
    int h = p>>6, f = p&63;
    unsigned int pr = *(const unsigned int*)&qr[h*128 + 2*f];
    float x0 = b2f((unsigned short)(pr & 0xffff)), x1 = b2f((unsigned short)(pr >> 16));
    float2 cssn = *(const float2*)&fc[t*128 + 2*f];
    float o0 = (x0*cssn.x - x1*cssn.y)*QS, o1 = (x0*cssn.y + x1*cssn.x)*QS;
    size_t o = ((size_t)(b*16 + h)*2048 + t)*128 + 2*f;
    qb[o] = f2b(o0); qb[o+1] = f2b(o1);
  }
  {                                   // 256 k pairs
    int p = tid; int kh = p>>6, f = p&63;
    unsigned int pr = *(const unsigned int*)&qr[2048 + kh*128 + 2*f];
    float x0 = b2f((unsigned short)(pr & 0xffff)), x1 = b2f((unsigned short)(pr >> 16));
    float2 cssn = *(const float2*)&fc[t*128 + 2*f];
    float o0 = x0*cssn.x - x1*cssn.y, o1 = x0*cssn.y + x1*cssn.x;
    size_t o = ((size_t)(b*4 + kh)*2048 + t)*128 + 2*f;
    kb[o] = f2b(o0); kb[o+1] = f2b(o1);
  }
  #pragma unroll
  for (int ii=0; ii<2; ii++){         // 512 v elems
    int e = tid + 256*ii;
    int kh = e>>7, d = e&127;
    size_t o = ((size_t)(b*4 + kh)*2048 + t)*128 + d;
    vb[o] = qr[2560 + e];
  }
}

// ---------------- V transpose: [bk][2048][128] -> [bk][128][2048] ----------------
__global__ void k_transpose_v(const unsigned short* __restrict__ v,
                              unsigned short* __restrict__ vt){
  __shared__ unsigned short tile[32][33];
  int bk = blockIdx.z;
  int d0 = blockIdx.x*32, t0 = blockIdx.y*32;
  int tx = threadIdx.x, ty = threadIdx.y;
  const unsigned short* vp = v + (size_t)bk*2048*128;
  unsigned short* vtp = vt + (size_t)bk*128*2048;
  #pragma unroll
  for (int i=0;i<4;i++) tile[ty*4+i][tx] = vp[(t0+ty*4+i)*128 + d0+tx];
  __syncthreads();
  #pragma unroll
  for (int i=0;i<4;i++) vtp[(d0+ty*4+i)*2048 + t0+tx] = tile[tx][ty*4+i];
}

// ---------------- sliding-window flash attention, LDS-staged K/V ----------------
__global__ __launch_bounds__(256,2) void k_attn(const unsigned short* __restrict__ q,
    const unsigned short* __restrict__ k, const unsigned short* __restrict__ vt,
    unsigned short* __restrict__ y){
  int qb0 = blockIdx.x*64;
  int h = blockIdx.y, b = blockIdx.z;
  int kvh = h>>2;
  int tid = threadIdx.x, wave = tid>>6, lane = tid&63;
  int w0 = qb0 + wave*16;
  int r = lane&15, g = lane>>4;
  const unsigned short* qh = q + ((size_t)(b*16+h)*2048)*128;
  const unsigned short* kh = k + ((size_t)(b*4+kvh)*2048)*128;
  const unsigned short* vh = vt + ((size_t)(b*4+kvh)*128)*2048;

  __shared__ unsigned short Ks[2][64*128];   // [key][d], swizzled
  __shared__ unsigned short Vs[2][128*64];   // [d][key], swizzled
  __shared__ unsigned short plds[4][16][72];

  short8 qf[4];
  #pragma unroll
  for (int c=0;c<4;c++) qf[c] = *(const short8*)&qh[(w0+r)*128 + c*32 + g*8];

  f32x4 acc[8];
  #pragma unroll
  for (int d=0; d<8; d++){ acc[d][0]=0.f; acc[d][1]=0.f; acc[d][2]=0.f; acc[d][3]=0.f; }
  float m[4]  = {-1e30f,-1e30f,-1e30f,-1e30f};
  float ls[4] = {0.f,0.f,0.f,0.f};

  int lo = qb0 - 511; if (lo < 0) lo = 0;
  int t0 = lo & ~63;
  int nt = ((qb0 + 63) - t0)/64 + 1;
  int sw = (r&7)<<4;                 // per-lane read swizzle (row&7 == r&7)

  #define STAGE(bb, kt)                                                          \
    { _Pragma("unroll")                                                          \
      for (int p=0;p<4;p++){                                                     \
        int c = p*256 + tid;                                                     \
        int row = c>>4, col = (c&15)*16;                                         \
        gld_lds16((const char*)kh + (size_t)((kt)+row)*256 + (col ^ ((row&7)<<4)),\
                  (char*)&Ks[bb][0] + c*16);                                     \
      }                                                                          \
      _Pragma("unroll")                                                          \
      for (int p=0;p<4;p++){                                                     \
        int c = p*256 + tid;                                                     \
        int row = c>>3, col = (c&7)*16;                                          \
        gld_lds16((const char*)vh + (size_t)row*4096 + (size_t)(kt)*2 + (col ^ ((row&7)<<4)),\
                  (char*)&Vs[bb][0] + c*16);                                     \
      }                                                                          \
    }

  STAGE(0, t0);
  __syncthreads();
  int cur = 0;

  for (int it=0; it<nt; it++){
    int kt = t0 + it*64;
    if (it+1 < nt) STAGE(cur^1, t0 + (it+1)*64);

    bool use = (kt <= w0+15) && (kt+63 >= w0-511);
    if (use){
      f32x4 S[4];
      #pragma unroll
      for (int s=0;s<4;s++){
        f32x4 a; a[0]=0.f; a[1]=0.f; a[2]=0.f; a[3]=0.f;
        const char* kr = (const char*)&Ks[cur][0] + (s*16+r)*256;
        #pragma unroll
        for (int c=0;c<4;c++){
          short8 kf = *(const short8*)(kr + ((c*64 + g*16) ^ sw));
          a = MFMA16(qf[c], kf, a);
        }
        S[s] = a;
      }
      #pragma unroll
      for (int rr=0;rr<4;rr++){
        int i = w0 + 4*g + rr;
        float mx = -3e38f;
        #pragma unroll
        for (int s=0;s<4;s++){
          int j = kt + s*16 + r;
          bool valid = (j <= i) && (i - j < 512);
          float sv = valid ? S[s][rr] : -3e38f;
          S[s][rr] = sv;
          mx = fmaxf(mx, sv);
        }
        mx = fmaxf(mx, __shfl_xor(mx, 1));
        mx = fmaxf(mx, __shfl_xor(mx, 2));
        mx = fmaxf(mx, __shfl_xor(mx, 4));
        mx = fmaxf(mx, __shfl_xor(mx, 8));
        float mn = fmaxf(m[rr], mx);
        float al = exp2f(m[rr] - mn);
        m[rr] = mn;
        float ps = 0.f;
        #pragma unroll
        for (int s=0;s<4;s++){
          float p = exp2f(S[s][rr] - mn);
          S[s][rr] = p;
          ps += p;
        }
        ls[rr] = ls[rr]*al + ps;
        #pragma unroll
        for (int d=0;d<8;d++) acc[d][rr] *= al;
      }
      #pragma unroll
      for (int rr=0;rr<4;rr++)
        #pragma unroll
        for (int s=0;s<4;s++)
          plds[wave][4*g+rr][s*16+r] = f2b(S[s][rr]);
      short8 pf0 = *(const short8*)&plds[wave][r][g*8];
      short8 pf1 = *(const short8*)&plds[wave][r][32 + g*8];
      #pragma unroll
      for (int d=0;d<8;d++){
        const char* vr = (const char*)&Vs[cur][0] + (d*16+r)*128;
        short8 vf0 = *(const short8*)(vr + ((g*16) ^ sw));
        short8 vf1 = *(const short8*)(vr + ((64 + g*16) ^ sw));
        acc[d] = MFMA16(pf0, vf0, acc[d]);
        acc[d] = MFMA16(pf1, vf1, acc[d]);
      }
    }
    __syncthreads();
    cur ^= 1;
  }

  #pragma unroll
  for (int rr=0;rr<4;rr++){
    float s = ls[rr];
    s += __shfl_xor(s, 1);
    s += __shfl_xor(s, 2);
    s += __shfl_xor(s, 4);
    s += __shfl_xor(s, 8);
    float inv = 1.f/s;
    int i = w0 + 4*g + rr;
    #pragma unroll
    for (int d=0;d<8;d++)
      y[((size_t)(b*2048)+i)*2048 + h*128 + d*16 + r] = f2b(acc[d][rr]*inv);
  }
}

extern "C" void kernel_launch(void* const* d_in, const int* in_sizes, int n_in,
                              void* d_out, int out_size, void* d_ws, size_t ws_size,
                              hipStream_t stream) {
  const float* x      = (const float*)d_in[0];
  const float* w_attn = (const float*)d_in[1];
  const float* w_proj = (const float*)d_in[2];
  const float* fc     = (const float*)d_in[3];
  float* out = (float*)d_out;
  char* ws = (char*)d_ws;
  unsigned short* xb   = (unsigned short*)(ws);             // 16,777,216
  unsigned short* wtA  = (unsigned short*)(ws + 16777216);  // 12,582,912
  unsigned short* wtP  = (unsigned short*)(ws + 29360128);  //  8,388,608
  unsigned short* qkvb = (unsigned short*)(ws + 37748736);  // 25,165,824
  unsigned short* yb   = (unsigned short*)(ws + 37748736);  // reuse after rope
  unsigned short* qb   = (unsigned short*)(ws + 62914560);  // 16,777,216
  unsigned short* kb   = (unsigned short*)(ws + 79691776);  //  4,194,304
  unsigned short* vb   = (unsigned short*)(ws + 83886080);  //  4,194,304
  unsigned short* vtb  = (unsigned short*)(ws + 88080384);  //  4,194,304

  k_prep<<<14336, 256, 0, stream>>>(x, w_attn, w_proj, xb, wtA, wtP);
  k_gemm97<1><<<dim3(768), 256, 0, stream>>>(xb, wtA, qkvb, 4096, 3072, 2048, 24);
  k_rope_split<<<4096, 256, 0, stream>>>(qkvb, fc, qb, kb, vb);
  k_transpose_v<<<dim3(4,64,8), dim3(32,8), 0, stream>>>(vb, vtb);
  k_attn<<<dim3(32,16,2), 256, 0, stream>>>(qb, kb, vtb, yb);
  k_gemm97<0><<<dim3(512), 256, 0, stream>>>(yb, wtP, out, 4096, 2048, 2048, 16);
}

// Round 8
// 174.989 us; speedup vs baseline: 1.5092x; 1.0360x over previous
//
#include <hip/hip_runtime.h>
#include <hip/hip_bf16.h>

typedef __attribute__((ext_vector_type(8))) short short8;
typedef __attribute__((ext_vector_type(4))) float f32x4;

#define MFMA16(a,b,c) __builtin_amdgcn_mfma_f32_16x16x32_bf16((a),(b),(c),0,0,0)

static __device__ __forceinline__ unsigned short f2b(float f){
  __hip_bfloat16 h = __float2bfloat16(f);
  return __builtin_bit_cast(unsigned short, h);
}
static __device__ __forceinline__ float b2f(unsigned short u){
  unsigned int v = ((unsigned int)u)<<16;
  return __builtin_bit_cast(float, v);
}

static __device__ __forceinline__ void gld_lds16(const void* g, void* l){
  __builtin_amdgcn_global_load_lds((const __attribute__((address_space(1))) unsigned int*)g,
                                   (__attribute__((address_space(3))) unsigned int*)l, 16, 0, 0);
}

// ---------------- fused prep: convert x + transpose-convert both weights ----------------
__global__ __launch_bounds__(256) void k_prep(const float* __restrict__ x,
    const float* __restrict__ wA, const float* __restrict__ wP,
    unsigned short* __restrict__ xb, unsigned short* __restrict__ wtA,
    unsigned short* __restrict__ wtP){
  int bid = blockIdx.x, tid = threadIdx.x;
  if (bid < 4096){
    int i = (bid*256 + tid)*8;
    float4 a = *(const float4*)(x+i);
    float4 b = *(const float4*)(x+i+4);
    short8 v;
    v[0]=f2b(a.x); v[1]=f2b(a.y); v[2]=f2b(a.z); v[3]=f2b(a.w);
    v[4]=f2b(b.x); v[5]=f2b(b.y); v[6]=f2b(b.z); v[7]=f2b(b.w);
    *(short8*)(xb+i) = v;
    return;
  }
  __shared__ float tile[32][33];
  const float* in; unsigned short* out; int R, C, bx, by;
  if (bid < 10240){ int tt = bid-4096;  in=wA; out=wtA; R=2048; C=3072; bx=tt%96; by=tt/96; }
  else            { int tt = bid-10240; in=wP; out=wtP; R=2048; C=2048; bx=tt%64; by=tt/64; }
  int c0 = bx*32, r0 = by*32;
  int tx = tid&31, ty = tid>>5;
  #pragma unroll
  for (int i=0;i<4;i++) tile[ty*4+i][tx] = in[(size_t)(r0+ty*4+i)*C + c0+tx];
  __syncthreads();
  #pragma unroll
  for (int i=0;i<4;i++) out[(size_t)(c0+ty*4+i)*R + r0+tx] = f2b(tile[tx][ty*4+i]);
}

// ---------------- 128x128 m97-structure bf16 GEMM: C = A[M][K] * BT[N][K]^T ----------------
template<int OB>   // OB=1: bf16 C out, OB=0: f32 C out
__global__ __launch_bounds__(256,2) void k_gemm97(const unsigned short* __restrict__ A,
    const unsigned short* __restrict__ BT, void* __restrict__ Cv,
    int M, int N, int K, int nbx){
  __shared__ __align__(16) unsigned short As[128*64];
  __shared__ __align__(16) unsigned short Bs[128*64];
  const int NT = K >> 6;
  int cpx = gridDim.x >> 3;
  int bid = blockIdx.x;
  int swz = (bid & 7)*cpx + (bid >> 3);
  int bm = (swz / nbx)*128, bn = (swz % nbx)*128;
  int tid = threadIdx.x;
  int wave = tid >> 6, lane = tid & 63;
  int r = lane & 15, g = lane >> 4;
  int wr = (wave >> 1)*64, wc = (wave & 1)*64;
  int sw = r & 7;

  f32x4 acc[4][4];
  #pragma unroll
  for (int i=0;i<4;i++)
    #pragma unroll
    for (int j=0;j<4;j++){ acc[i][j][0]=0.f; acc[i][j][1]=0.f; acc[i][j][2]=0.f; acc[i][j][3]=0.f; }

  for (int t=0; t<NT; ++t){
    #pragma unroll
    for (int i=0;i<4;i++){
      int c = i*256 + tid;
      int row = c>>3, kc = c&7;
      gld_lds16(&A[(size_t)(bm+row)*K + (size_t)t*64 + ((kc^(row&7))*8)], (char*)As + c*16);
    }
    #pragma unroll
    for (int i=0;i<4;i++){
      int c = i*256 + tid;
      int row = c>>3, kc = c&7;
      gld_lds16(&BT[(size_t)(bn+row)*K + (size_t)t*64 + ((kc^(row&7))*8)], (char*)Bs + c*16);
    }
    __syncthreads();
    short8 af[4][2], bf[4][2];
    #pragma unroll
    for (int i=0;i<4;i++)
      #pragma unroll
      for (int kk=0;kk<2;kk++){
        int row = wr + i*16 + r;
        af[i][kk] = *(const short8*)((const char*)As + ((size_t)(row*8 + ((kk*4+g)^sw))<<4));
      }
    #pragma unroll
    for (int j=0;j<4;j++)
      #pragma unroll
      for (int kk=0;kk<2;kk++){
        int row = wc + j*16 + r;
        bf[j][kk] = *(const short8*)((const char*)Bs + ((size_t)(row*8 + ((kk*4+g)^sw))<<4));
      }
    #pragma unroll
    for (int kk=0;kk<2;kk++)
      #pragma unroll
      for (int i=0;i<4;i++)
        #pragma unroll
        for (int j=0;j<4;j++)
          acc[i][j] = MFMA16(af[i][kk], bf[j][kk], acc[i][j]);
    __syncthreads();
  }

  #pragma unroll
  for (int i=0;i<4;i++)
    #pragma unroll
    for (int j=0;j<4;j++)
      #pragma unroll
      for (int rr=0;rr<4;rr++){
        size_t idx = (size_t)(bm + wr + i*16 + 4*g + rr)*N + bn + wc + j*16 + r;
        if (OB) ((unsigned short*)Cv)[idx] = f2b(acc[i][j][rr]);
        else    ((float*)Cv)[idx] = acc[i][j][rr];
      }
}

// ---------------- RoPE + head split (bf16 qkv in); Q scaled by log2(e)/sqrt(128) ----------------
__global__ __launch_bounds__(256) void k_rope_split(const unsigned short* __restrict__ qkv,
    const float* __restrict__ fc, unsigned short* __restrict__ qb,
    unsigned short* __restrict__ kb, unsigned short* __restrict__ vb){
  int row = blockIdx.x;              // b*2048 + t
  int t = row & 2047, b = row >> 11;
  int tid = threadIdx.x;
  const unsigned short* qr = qkv + (size_t)row*3072;
  const float QS = 0.12751743f;      // log2(e)/sqrt(128)
  #pragma unroll
  for (int ii=0; ii<4; ii++){        // 1024 q pairs
    int p = tid + 256*ii;
    int h = p>>6, f = p&63;
    unsigned int pr = *(const unsigned int*)&qr[h*128 + 2*f];
    float x0 = b2f((unsigned short)(pr & 0xffff)), x1 = b2f((unsigned short)(pr >> 16));
    float2 cssn = *(const float2*)&fc[t*128 + 2*f];
    float o0 = (x0*cssn.x - x1*cssn.y)*QS, o1 = (x0*cssn.y + x1*cssn.x)*QS;
    size_t o = ((size_t)(b*16 + h)*2048 + t)*128 + 2*f;
    qb[o] = f2b(o0); qb[o+1] = f2b(o1);
  }
  {                                   // 256 k pairs
    int p = tid; int kh = p>>6, f = p&63;
    unsigned int pr = *(const unsigned int*)&qr[2048 + kh*128 + 2*f];
    float x0 = b2f((unsigned short)(pr & 0xffff)), x1 = b2f((unsigned short)(pr >> 16));
    float2 cssn = *(const float2*)&fc[t*128 + 2*f];
    float o0 = x0*cssn.x - x1*cssn.y, o1 = x0*cssn.y + x1*cssn.x;
    size_t o = ((size_t)(b*4 + kh)*2048 + t)*128 + 2*f;
    kb[o] = f2b(o0); kb[o+1] = f2b(o1);
  }
  #pragma unroll
  for (int ii=0; ii<2; ii++){         // 512 v elems
    int e = tid + 256*ii;
    int kh = e>>7, d = e&127;
    size_t o = ((size_t)(b*4 + kh)*2048 + t)*128 + d;
    vb[o] = qr[2560 + e];
  }
}

// ---------------- V transpose: [bk][2048][128] -> [bk][128][2048] ----------------
__global__ void k_transpose_v(const unsigned short* __restrict__ v,
                              unsigned short* __restrict__ vt){
  __shared__ unsigned short tile[32][33];
  int bk = blockIdx.z;
  int d0 = blockIdx.x*32, t0 = blockIdx.y*32;
  int tx = threadIdx.x, ty = threadIdx.y;
  const unsigned short* vp = v + (size_t)bk*2048*128;
  unsigned short* vtp = vt + (size_t)bk*128*2048;
  #pragma unroll
  for (int i=0;i<4;i++) tile[ty*4+i][tx] = vp[(t0+ty*4+i)*128 + d0+tx];
  __syncthreads();
  #pragma unroll
  for (int i=0;i<4;i++) vtp[(d0+ty*4+i)*2048 + t0+tx] = tile[tx][ty*4+i];
}

// ---------------- sliding-window flash attention, two q-strips per wave ----------------
// grid (T/128, H, B); 4 waves x 2x16 q-rows. K/V double-buffered LDS (XOR-swizzled,
// both-sides). Strips A/B share K-frag and V-frag loads; independent softmax chains
// interleave for 2x ILP on the latency-bound shuffle/exp path.
__global__ __launch_bounds__(256,2) void k_attn(const unsigned short* __restrict__ q,
    const unsigned short* __restrict__ k, const unsigned short* __restrict__ vt,
    unsigned short* __restrict__ y){
  int qb0 = blockIdx.x*128;
  int h = blockIdx.y, b = blockIdx.z;
  int kvh = h>>2;
  int tid = threadIdx.x, wave = tid>>6, lane = tid&63;
  int w0A = qb0 + wave*32, w0B = w0A + 16;
  int r = lane&15, g = lane>>4;
  const unsigned short* qh = q + ((size_t)(b*16+h)*2048)*128;
  const unsigned short* kh = k + ((size_t)(b*4+kvh)*2048)*128;
  const unsigned short* vh = vt + ((size_t)(b*4+kvh)*128)*2048;

  __shared__ unsigned short Ks[2][64*128];   // [key][d], swizzled
  __shared__ unsigned short Vs[2][128*64];   // [d][key], swizzled
  __shared__ unsigned short plds[4][16][72];

  short8 qfA[4], qfB[4];
  #pragma unroll
  for (int c=0;c<4;c++){
    qfA[c] = *(const short8*)&qh[(w0A+r)*128 + c*32 + g*8];
    qfB[c] = *(const short8*)&qh[(w0B+r)*128 + c*32 + g*8];
  }

  f32x4 accA[8], accB[8];
  #pragma unroll
  for (int d=0; d<8; d++){
    accA[d][0]=0.f; accA[d][1]=0.f; accA[d][2]=0.f; accA[d][3]=0.f;
    accB[d][0]=0.f; accB[d][1]=0.f; accB[d][2]=0.f; accB[d][3]=0.f;
  }
  float mA[4]  = {-1e30f,-1e30f,-1e30f,-1e30f};
  float mB[4]  = {-1e30f,-1e30f,-1e30f,-1e30f};
  float lsA[4] = {0.f,0.f,0.f,0.f};
  float lsB[4] = {0.f,0.f,0.f,0.f};

  int lo = qb0 - 511; if (lo < 0) lo = 0;
  int t0 = lo & ~63;
  int nt = ((qb0 + 127) - t0)/64 + 1;
  int sw = (r&7)<<4;                 // per-lane read swizzle

  #define STAGE(bb, kt)                                                          \
    { _Pragma("unroll")                                                          \
      for (int p=0;p<4;p++){                                                     \
        int c = p*256 + tid;                                                     \
        int row = c>>4, col = (c&15)*16;                                         \
        gld_lds16((const char*)kh + (size_t)((kt)+row)*256 + (col ^ ((row&7)<<4)),\
                  (char*)&Ks[bb][0] + c*16);                                     \
      }                                                                          \
      _Pragma("unroll")                                                          \
      for (int p=0;p<4;p++){                                                     \
        int c = p*256 + tid;                                                     \
        int row = c>>3, col = (c&7)*16;                                          \
        gld_lds16((const char*)vh + (size_t)row*4096 + (size_t)(kt)*2 + (col ^ ((row&7)<<4)),\
                  (char*)&Vs[bb][0] + c*16);                                     \
      }                                                                          \
    }

  STAGE(0, t0);
  __syncthreads();
  int cur = 0;

  for (int it=0; it<nt; it++){
    int kt = t0 + it*64;
    if (it+1 < nt) STAGE(cur^1, kt + 64);

    bool useA = (kt <= w0A+15) && (kt+63 >= w0A-511);
    bool useB = (kt <= w0B+15) && (kt+63 >= w0B-511);
    if (useA || useB){
      // ---- QK^T for both strips, shared K fragments ----
      f32x4 SA[4], SB[4];
      #pragma unroll
      for (int s=0;s<4;s++){
        f32x4 aA; aA[0]=0.f; aA[1]=0.f; aA[2]=0.f; aA[3]=0.f;
        f32x4 aB; aB[0]=0.f; aB[1]=0.f; aB[2]=0.f; aB[3]=0.f;
        const char* kr = (const char*)&Ks[cur][0] + (s*16+r)*256;
        #pragma unroll
        for (int c=0;c<4;c++){
          short8 kf = *(const short8*)(kr + ((c*64 + g*16) ^ sw));
          aA = MFMA16(qfA[c], kf, aA);
          aB = MFMA16(qfB[c], kf, aB);
        }
        SA[s] = aA; SB[s] = aB;
      }
      // ---- mask + in-lane max, both strips ----
      float mxA[4], mxB[4];
      #pragma unroll
      for (int rr=0;rr<4;rr++){
        int iA = w0A + 4*g + rr, iB = w0B + 4*g + rr;
        float ma = -3e38f, mb_ = -3e38f;
        #pragma unroll
        for (int s=0;s<4;s++){
          int j = kt + s*16 + r;
          bool vA = (j <= iA) && (iA - j < 512);
          bool vB = (j <= iB) && (iB - j < 512);
          float sa = vA ? SA[s][rr] : -3e38f;
          float sb = vB ? SB[s][rr] : -3e38f;
          SA[s][rr] = sa; SB[s][rr] = sb;
          ma = fmaxf(ma, sa); mb_ = fmaxf(mb_, sb);
        }
        mxA[rr] = ma; mxB[rr] = mb_;
      }
      // ---- shuffle reduce: 8 independent chains interleave ----
      #pragma unroll
      for (int st=1; st<16; st<<=1){
        #pragma unroll
        for (int rr=0;rr<4;rr++){
          mxA[rr] = fmaxf(mxA[rr], __shfl_xor(mxA[rr], st));
          mxB[rr] = fmaxf(mxB[rr], __shfl_xor(mxB[rr], st));
        }
      }
      // ---- online softmax update, both strips ----
      #pragma unroll
      for (int rr=0;rr<4;rr++){
        float mnA = fmaxf(mA[rr], mxA[rr]);
        float mnB = fmaxf(mB[rr], mxB[rr]);
        float alA = exp2f(mA[rr] - mnA);
        float alB = exp2f(mB[rr] - mnB);
        mA[rr] = mnA; mB[rr] = mnB;
        float psA = 0.f, psB = 0.f;
        #pragma unroll
        for (int s=0;s<4;s++){
          float pa = exp2f(SA[s][rr] - mnA);
          float pb = exp2f(SB[s][rr] - mnB);
          SA[s][rr] = pa; SB[s][rr] = pb;
          psA += pa; psB += pb;
        }
        lsA[rr] = lsA[rr]*alA + psA;
        lsB[rr] = lsB[rr]*alB + psB;
        #pragma unroll
        for (int d=0;d<8;d++){ accA[d][rr] *= alA; accB[d][rr] *= alB; }
      }
      // ---- P relayout via per-wave LDS (A then B, in-order DS) ----
      #pragma unroll
      for (int rr=0;rr<4;rr++)
        #pragma unroll
        for (int s=0;s<4;s++)
          plds[wave][4*g+rr][s*16+r] = f2b(SA[s][rr]);
      short8 pfA0 = *(const short8*)&plds[wave][r][g*8];
      short8 pfA1 = *(const short8*)&plds[wave][r][32 + g*8];
      #pragma unroll
      for (int rr=0;rr<4;rr++)
        #pragma unroll
        for (int s=0;s<4;s++)
          plds[wave][4*g+rr][s*16+r] = f2b(SB[s][rr]);
      short8 pfB0 = *(const short8*)&plds[wave][r][g*8];
      short8 pfB1 = *(const short8*)&plds[wave][r][32 + g*8];
      // ---- PV, shared V fragments ----
      #pragma unroll
      for (int d=0;d<8;d++){
        const char* vr = (const char*)&Vs[cur][0] + (d*16+r)*128;
        short8 vf0 = *(const short8*)(vr + ((g*16) ^ sw));
        short8 vf1 = *(const short8*)(vr + ((64 + g*16) ^ sw));
        accA[d] = MFMA16(pfA0, vf0, accA[d]);
        accA[d] = MFMA16(pfA1, vf1, accA[d]);
        accB[d] = MFMA16(pfB0, vf0, accB[d]);
        accB[d] = MFMA16(pfB1, vf1, accB[d]);
      }
    }
    __syncthreads();
    cur ^= 1;
  }

  #pragma unroll
  for (int rr=0;rr<4;rr++){
    float sa = lsA[rr], sb = lsB[rr];
    #pragma unroll
    for (int st=1; st<16; st<<=1){ sa += __shfl_xor(sa, st); sb += __shfl_xor(sb, st); }
    float invA = 1.f/sa, invB = 1.f/sb;
    int iA = w0A + 4*g + rr, iB = w0B + 4*g + rr;
    #pragma unroll
    for (int d=0;d<8;d++){
      y[((size_t)(b*2048)+iA)*2048 + h*128 + d*16 + r] = f2b(accA[d][rr]*invA);
      y[((size_t)(b*2048)+iB)*2048 + h*128 + d*16 + r] = f2b(accB[d][rr]*invB);
    }
  }
}

extern "C" void kernel_launch(void* const* d_in, const int* in_sizes, int n_in,
                              void* d_out, int out_size, void* d_ws, size_t ws_size,
                              hipStream_t stream) {
  const float* x      = (const float*)d_in[0];
  const float* w_attn = (const float*)d_in[1];
  const float* w_proj = (const float*)d_in[2];
  const float* fc     = (const float*)d_in[3];
  float* out = (float*)d_out;
  char* ws = (char*)d_ws;
  unsigned short* xb   = (unsigned short*)(ws);             // 16,777,216
  unsigned short* wtA  = (unsigned short*)(ws + 16777216);  // 12,582,912
  unsigned short* wtP  = (unsigned short*)(ws + 29360128);  //  8,388,608
  unsigned short* qkvb = (unsigned short*)(ws + 37748736);  // 25,165,824
  unsigned short* yb   = (unsigned short*)(ws + 37748736);  // reuse after rope
  unsigned short* qb   = (unsigned short*)(ws + 62914560);  // 16,777,216
  unsigned short* kb   = (unsigned short*)(ws + 79691776);  //  4,194,304
  unsigned short* vb   = (unsigned short*)(ws + 83886080);  //  4,194,304
  unsigned short* vtb  = (unsigned short*)(ws + 88080384);  //  4,194,304

  k_prep<<<14336, 256, 0, stream>>>(x, w_attn, w_proj, xb, wtA, wtP);
  k_gemm97<1><<<dim3(768), 256, 0, stream>>>(xb, wtA, qkvb, 4096, 3072, 2048, 24);
  k_rope_split<<<4096, 256, 0, stream>>>(qkvb, fc, qb, kb, vb);
  k_transpose_v<<<dim3(4,64,8), dim3(32,8), 0, stream>>>(vb, vtb);
  k_attn<<<dim3(16,16,2), 256, 0, stream>>>(qb, kb, vtb, yb);
  k_gemm97<0><<<dim3(512), 256, 0, stream>>>(yb, wtP, out, 4096, 2048, 2048, 16);
}